// Round 3
// baseline (32.746 us; speedup 1.0000x reference)
//
#include <hip/hip_runtime.h>
#include <hip/hip_bf16.h>

// ---------------------------------------------------------------------------
// QuantumNeuralNetwork: out[b][q] = <psi_b| U^dag Z_q U |psi_b>.
// Kernel 1: build W = [Re(U); Im(U)] (128x128 bf16 x2) in d_ws.
// Kernel 2: per 64-row tile, double-buffered pipeline with ONE barrier/iter:
//   tail(t-s) || MFMA-compute(t) || stage(t+s)+prefetch(t+2s)  -> s_barrier
// ---------------------------------------------------------------------------

typedef __attribute__((ext_vector_type(8)))  short short8;   // 8 x bf16
typedef __attribute__((ext_vector_type(16))) float f32x16;   // 32x32 acc

static __device__ __forceinline__ short f2bf(float f) {
  __bf16 h = (__bf16)f;
  return __builtin_bit_cast(short, h);
}

// ------------------------------- kernel 1 ----------------------------------
// 128 blocks (one column k each) x 64 threads. Lane l holds states 2l, 2l+1.
__global__ void qnn_build_w(const float* __restrict__ wts,
                            short* __restrict__ W) {
  const int k = blockIdx.x;
  const int l = threadIdx.x;

  float c0r = (2 * l     == k) ? 1.f : 0.f, c0i = 0.f;
  float c1r = (2 * l + 1 == k) ? 1.f : 0.f, c1i = 0.f;

  for (int layer = 0; layer < 2; ++layer) {
    for (int q = 0; q < 7; ++q) {
      const float t0 = 0.5f * wts[(layer * 7 + q) * 3 + 0];
      const float t1 = 0.5f * wts[(layer * 7 + q) * 3 + 1];
      const float t2 = 0.5f * wts[(layer * 7 + q) * 3 + 2];
      const float cx = cosf(t0), sx = sinf(t0);
      const float cy = cosf(t1), sy = sinf(t1);
      const float cz = cosf(t2), sz = sinf(t2);
      const float m00r =  cy * cx, m00i =  sy * sx;
      const float m01r = -sy * cx, m01i = -cy * sx;
      const float m10r =  sy * cx, m10i = -cy * sx;
      const float m11r =  cy * cx, m11i = -sy * sx;
      const float g00r = m00r * cz + m00i * sz, g00i = m00i * cz - m00r * sz;
      const float g01r = m01r * cz + m01i * sz, g01i = m01i * cz - m01r * sz;
      const float g10r = m10r * cz - m10i * sz, g10i = m10i * cz + m10r * sz;
      const float g11r = m11r * cz - m11i * sz, g11i = m11i * cz + m11r * sz;

      const int b = 6 - q;
      if (b == 0) {
        const float n0r = g00r*c0r - g00i*c0i + g01r*c1r - g01i*c1i;
        const float n0i = g00r*c0i + g00i*c0r + g01r*c1i + g01i*c1r;
        const float n1r = g10r*c0r - g10i*c0i + g11r*c1r - g11i*c1i;
        const float n1i = g10r*c0i + g10i*c0r + g11r*c1i + g11i*c1r;
        c0r = n0r; c0i = n0i; c1r = n1r; c1i = n1i;
      } else {
        const int xm  = 1 << (b - 1);
        const int myb = (l >> (b - 1)) & 1;
        const float p0r = __shfl_xor(c0r, xm), p0i = __shfl_xor(c0i, xm);
        const float p1r = __shfl_xor(c1r, xm), p1i = __shfl_xor(c1i, xm);
        const float gar = myb ? g11r : g00r, gai = myb ? g11i : g00i;
        const float gbr = myb ? g10r : g01r, gbi = myb ? g10i : g01i;
        const float n0r = gar*c0r - gai*c0i + gbr*p0r - gbi*p0i;
        const float n0i = gar*c0i + gai*c0r + gbr*p0i + gbi*p0r;
        const float n1r = gar*c1r - gai*c1i + gbr*p1r - gbi*p1i;
        const float n1i = gar*c1i + gai*c1r + gbr*p1i + gbi*p1r;
        c0r = n0r; c0i = n0i; c1r = n1r; c1i = n1i;
      }
    }
    #pragma unroll
    for (int q = 0; q < 7; ++q) {
      const int bc = 6 - q;
      const int bt = 6 - ((q + 1) % 7);
      if (bt == 0) {
        if (l & 1) { float tr=c0r, ti=c0i; c0r=c1r; c0i=c1i; c1r=tr; c1i=ti; }
      } else if (bc == 0) {
        c1r = __shfl_xor(c1r, 32);
        c1i = __shfl_xor(c1i, 32);
      } else {
        const int xm = 1 << (bt - 1);
        const float p0r = __shfl_xor(c0r, xm), p0i = __shfl_xor(c0i, xm);
        const float p1r = __shfl_xor(c1r, xm), p1i = __shfl_xor(c1i, xm);
        if ((l >> (bc - 1)) & 1) { c0r=p0r; c0i=p0i; c1r=p1r; c1i=p1i; }
      }
    }
  }

  W[(2 * l)     * 128 + k]         = f2bf(c0r);
  W[(2 * l + 1) * 128 + k]         = f2bf(c1r);
  W[16384 + (2 * l)     * 128 + k] = f2bf(c0i);
  W[16384 + (2 * l + 1) * 128 + k] = f2bf(c1i);
}

// ------------------------------- kernel 2 ----------------------------------
// 256 threads (4 waves). 64 rows/iter. Wave wv owns states [32wv,32wv+32)
// (A slice, 64 VGPRs). x staged bf16 in double-buffered swizzled LDS.
// One barrier per iteration; global prefetch depth 2 (t+s in regs, t+2s in
// flight); partial-reduction buffer red[] is also double-buffered so the
// output write of tile t-s overlaps the compute of tile t.
__global__ __launch_bounds__(256, 2) void qnn_main(
    const float* __restrict__ x, const short* __restrict__ W,
    float* __restrict__ out, int niter, int stride) {
  const int tid = threadIdx.x;
  const int l   = tid & 63;
  const int wv  = tid >> 6;
  const int col = l & 31;
  const int h   = l >> 5;

  __shared__ short8 xb[2][1024];      // 2 x (64 rows x 16 chunks), 32 KiB
  __shared__ float  red[2][4][64][6]; // 12 KiB

  // Preload this wave's W slice: 16 frags of 8 bf16 = 64 VGPRs.
  short8 A0[8], A1[8];
  #pragma unroll
  for (int j = 0; j < 8; ++j) {
    const int off = (32 * wv + col) * 128 + j * 16 + h * 8;
    A0[j] = *reinterpret_cast<const short8*>(W + off);
    A1[j] = *reinterpret_cast<const short8*>(W + 16384 + off);
  }

  float4 fa[4], fb[4];

  auto LOADT = [&](int T) {
    #pragma unroll
    for (int i = 0; i < 4; ++i) {
      const int pp = i * 256 + tid;
      const int r = pp >> 4, q = pp & 15;
      const float* gp = x + (size_t)(T * 64 + r) * 128 + q * 8;
      fa[i] = *reinterpret_cast<const float4*>(gp);
      fb[i] = *reinterpret_cast<const float4*>(gp + 4);
    }
  };
  auto STAGE = [&](int buf) {
    #pragma unroll
    for (int i = 0; i < 4; ++i) {
      const int pp = i * 256 + tid;
      const int r = pp >> 4, q = pp & 15;
      short8 c;
      c[0]=f2bf(fa[i].x); c[1]=f2bf(fa[i].y); c[2]=f2bf(fa[i].z); c[3]=f2bf(fa[i].w);
      c[4]=f2bf(fb[i].x); c[5]=f2bf(fb[i].y); c[6]=f2bf(fb[i].z); c[7]=f2bf(fb[i].w);
      xb[buf][r * 16 + (q ^ (r & 7))] = c;
    }
  };
  auto TAIL = [&](int buf, int T) {
    if (tid < 64) {
      const int c = tid;
      const float T0 = red[buf][0][c][0], T1 = red[buf][1][c][0];
      const float T2 = red[buf][2][c][0], T3 = red[buf][3][c][0];
      const float sT  = (T0 + T1) + (T2 + T3);
      const float inv = 1.0f / sT;          // == 1/||x||^2 (unitarity)
      const float z0 = (T0 + T1) - (T2 + T3);
      const float z1 = (T0 - T1) + (T2 - T3);
      float zr[5];
      #pragma unroll
      for (int i = 0; i < 5; ++i)
        zr[i] = (red[buf][0][c][5-i] + red[buf][1][c][5-i]) +
                (red[buf][2][c][5-i] + red[buf][3][c][5-i]);
      float* o = out + (size_t)(T * 64 + c) * 7;
      o[0] = z0 * inv; o[1] = z1 * inv; o[2] = zr[0] * inv; o[3] = zr[1] * inv;
      o[4] = zr[2] * inv; o[5] = zr[3] * inv; o[6] = zr[4] * inv;
    }
  };

  int t = blockIdx.x;

  // ---- prologue: tile t -> xb[0]; issue loads for t+stride
  LOADT(t);
  STAGE(0);
  if (t + stride < niter) LOADT(t + stride);
  asm volatile("s_waitcnt lgkmcnt(0)" ::: "memory");
  __builtin_amdgcn_s_barrier();
  asm volatile("" ::: "memory");

  int k = 0;
  int lastT = t, lastP = 0;
  for (; t < niter; t += stride, ++k) {
    const int p = k & 1;
    lastT = t; lastP = p;

    // ---- output write for tile t-stride (overlaps compute below)
    if (k > 0) TAIL(p ^ 1, t - stride);

    // ---- compute tile t from xb[p]; per-g epilogue -> red[p]
    const short8* xbuf = xb[p];
    #pragma unroll
    for (int g = 0; g < 2; ++g) {
      f32x16 acc0 = {0.f,0.f,0.f,0.f,0.f,0.f,0.f,0.f,
                     0.f,0.f,0.f,0.f,0.f,0.f,0.f,0.f};
      f32x16 acc1 = {0.f,0.f,0.f,0.f,0.f,0.f,0.f,0.f,
                     0.f,0.f,0.f,0.f,0.f,0.f,0.f,0.f};
      const int r = g * 32 + col;
      #pragma unroll
      for (int j = 0; j < 8; ++j) {
        const int q = j * 2 + h;
        const short8 bfr = xbuf[r * 16 + (q ^ (r & 7))];
        acc0 = __builtin_amdgcn_mfma_f32_32x32x16_bf16(A0[j], bfr, acc0, 0, 0, 0);
        acc1 = __builtin_amdgcn_mfma_f32_32x32x16_bf16(A1[j], bfr, acc1, 0, 0, 0);
      }
      // Walsh tree over s-bits
      float aS[8], aD[8];
      #pragma unroll
      for (int i = 0; i < 8; ++i) {
        const float pe = acc0[2*i]   * acc0[2*i]   + acc1[2*i]   * acc1[2*i];
        const float po = acc0[2*i+1] * acc0[2*i+1] + acc1[2*i+1] * acc1[2*i+1];
        aS[i] = pe + po;
        aD[i] = pe - po;
      }
      float bS[4], bD[4];
      #pragma unroll
      for (int i = 0; i < 4; ++i) {
        bS[i] = aS[2*i] + aS[2*i+1];
        bD[i] = aS[2*i] - aS[2*i+1];
      }
      float u0 = ((aD[0]+aD[1]) + (aD[2]+aD[3])) + ((aD[4]+aD[5]) + (aD[6]+aD[7]));
      float u1 = (bD[0] + bD[1]) + (bD[2] + bD[3]);
      const float cS0 = bS[0] + bS[1], cD0 = bS[0] - bS[1];
      const float cS1 = bS[2] + bS[3], cD1 = bS[2] - bS[3];
      float u3 = cD0 + cD1;
      float u4 = cS0 - cS1;
      float T  = cS0 + cS1;

      const float Tp = __shfl_xor(T, 32);
      const float u2 = h ? (Tp - T) : (T - Tp);
      T += Tp;
      u0 += __shfl_xor(u0, 32);
      u1 += __shfl_xor(u1, 32);
      u3 += __shfl_xor(u3, 32);
      u4 += __shfl_xor(u4, 32);

      if (h == 0) {
        red[p][wv][r][0] = T;
        red[p][wv][r][1] = u0;
        red[p][wv][r][2] = u1;
        red[p][wv][r][3] = u2;
        red[p][wv][r][4] = u3;
        red[p][wv][r][5] = u4;
      }
    }

    // ---- stage tile t+stride into xb[p^1]; issue loads for t+2*stride
    if (t + stride < niter) {
      STAGE(p ^ 1);
      if (t + 2 * stride < niter) LOADT(t + 2 * stride);
    }

    asm volatile("s_waitcnt lgkmcnt(0)" ::: "memory");
    __builtin_amdgcn_s_barrier();
    asm volatile("" ::: "memory");
  }

  // ---- drain: last tile's outputs
  TAIL(lastP, lastT);
}

// ------------------------------- launcher ----------------------------------
extern "C" void kernel_launch(void* const* d_in, const int* in_sizes, int n_in,
                              void* d_out, int out_size, void* d_ws, size_t ws_size,
                              hipStream_t stream) {
  const float* x   = (const float*)d_in[0];
  const float* wts = (const float*)d_in[1];
  float* out = (float*)d_out;
  short* W   = (short*)d_ws;               // 2 * 128*128 bf16 = 64 KiB

  const int B     = in_sizes[0] / 128;
  const int niter = B / 64;
  const int grid  = niter < 512 ? niter : 512;

  qnn_build_w<<<128, 64, 0, stream>>>(wts, W);
  qnn_main<<<grid, 256, 0, stream>>>(x, W, out, niter, grid);
}

// Round 4
// 26.046 us; speedup vs baseline: 1.2572x; 1.2572x over previous
//
#include <hip/hip_runtime.h>
#include <hip/hip_bf16.h>

// ---------------------------------------------------------------------------
// QuantumNeuralNetwork: out[b][q] = <psi_b| U^dag Z_q U |psi_b>.
// Kernel 1: build W = [Re(U); Im(U)] as 128x128 bf16 x2 in d_ws, stored in
//           MFMA-A-fragment order (coalesced per-wave preload).
// Kernel 2: grid = niter/2 blocks; each block handles 2 independent 64-row
//           tiles (all global loads issued up front), 3 barriers total.
//           TLP across 3 blocks/CU does the latency hiding.
// ---------------------------------------------------------------------------

typedef __attribute__((ext_vector_type(8)))  short short8;   // 8 x bf16
typedef __attribute__((ext_vector_type(16))) float f32x16;   // 32x32 acc

static __device__ __forceinline__ short f2bf(float f) {
  __bf16 h = (__bf16)f;
  return __builtin_bit_cast(short, h);
}

// A-fragment layout: frag(P, wv=s>>5, j=k>>4); lane = (s&31) + 32*((k>>3)&1);
// elem = k&7.  Flat short index:
static __device__ __forceinline__ int widx(int P, int s, int k) {
  return ((((P << 2) + (s >> 5)) * 8 + (k >> 4)) * 64 +
          ((s & 31) + ((k >> 3) & 1) * 32)) * 8 + (k & 7);
}

// ------------------------------- kernel 1 ----------------------------------
// 128 blocks (one column k each) x 64 threads. Lane l holds states 2l, 2l+1.
__global__ void qnn_build_w(const float* __restrict__ wts,
                            short* __restrict__ W) {
  const int k = blockIdx.x;
  const int l = threadIdx.x;

  float c0r = (2 * l     == k) ? 1.f : 0.f, c0i = 0.f;
  float c1r = (2 * l + 1 == k) ? 1.f : 0.f, c1i = 0.f;

  for (int layer = 0; layer < 2; ++layer) {
    for (int q = 0; q < 7; ++q) {
      const float t0 = 0.5f * wts[(layer * 7 + q) * 3 + 0];
      const float t1 = 0.5f * wts[(layer * 7 + q) * 3 + 1];
      const float t2 = 0.5f * wts[(layer * 7 + q) * 3 + 2];
      const float cx = __cosf(t0), sx = __sinf(t0);
      const float cy = __cosf(t1), sy = __sinf(t1);
      const float cz = __cosf(t2), sz = __sinf(t2);
      const float m00r =  cy * cx, m00i =  sy * sx;
      const float m01r = -sy * cx, m01i = -cy * sx;
      const float m10r =  sy * cx, m10i = -cy * sx;
      const float m11r =  cy * cx, m11i = -sy * sx;
      const float g00r = m00r * cz + m00i * sz, g00i = m00i * cz - m00r * sz;
      const float g01r = m01r * cz + m01i * sz, g01i = m01i * cz - m01r * sz;
      const float g10r = m10r * cz - m10i * sz, g10i = m10i * cz + m10r * sz;
      const float g11r = m11r * cz - m11i * sz, g11i = m11i * cz + m11r * sz;

      const int b = 6 - q;
      if (b == 0) {
        const float n0r = g00r*c0r - g00i*c0i + g01r*c1r - g01i*c1i;
        const float n0i = g00r*c0i + g00i*c0r + g01r*c1i + g01i*c1r;
        const float n1r = g10r*c0r - g10i*c0i + g11r*c1r - g11i*c1i;
        const float n1i = g10r*c0i + g10i*c0r + g11r*c1i + g11i*c1r;
        c0r = n0r; c0i = n0i; c1r = n1r; c1i = n1i;
      } else {
        const int xm  = 1 << (b - 1);
        const int myb = (l >> (b - 1)) & 1;
        const float p0r = __shfl_xor(c0r, xm), p0i = __shfl_xor(c0i, xm);
        const float p1r = __shfl_xor(c1r, xm), p1i = __shfl_xor(c1i, xm);
        const float gar = myb ? g11r : g00r, gai = myb ? g11i : g00i;
        const float gbr = myb ? g10r : g01r, gbi = myb ? g10i : g01i;
        const float n0r = gar*c0r - gai*c0i + gbr*p0r - gbi*p0i;
        const float n0i = gar*c0i + gai*c0r + gbr*p0i + gbi*p0r;
        const float n1r = gar*c1r - gai*c1i + gbr*p1r - gbi*p1i;
        const float n1i = gar*c1i + gai*c1r + gbr*p1i + gbi*p1r;
        c0r = n0r; c0i = n0i; c1r = n1r; c1i = n1i;
      }
    }
    #pragma unroll
    for (int q = 0; q < 7; ++q) {
      const int bc = 6 - q;
      const int bt = 6 - ((q + 1) % 7);
      if (bt == 0) {
        if (l & 1) { float tr=c0r, ti=c0i; c0r=c1r; c0i=c1i; c1r=tr; c1i=ti; }
      } else if (bc == 0) {
        c1r = __shfl_xor(c1r, 32);
        c1i = __shfl_xor(c1i, 32);
      } else {
        const int xm = 1 << (bt - 1);
        const float p0r = __shfl_xor(c0r, xm), p0i = __shfl_xor(c0i, xm);
        const float p1r = __shfl_xor(c1r, xm), p1i = __shfl_xor(c1i, xm);
        if ((l >> (bc - 1)) & 1) { c0r=p0r; c0i=p0i; c1r=p1r; c1i=p1i; }
      }
    }
  }

  W[widx(0, 2 * l,     k)] = f2bf(c0r);
  W[widx(0, 2 * l + 1, k)] = f2bf(c1r);
  W[widx(1, 2 * l,     k)] = f2bf(c0i);
  W[widx(1, 2 * l + 1, k)] = f2bf(c1i);
}

// ------------------------------- kernel 2 ----------------------------------
// 256 threads (4 waves), 2 independent 64-row tiles per block.
// Wave wv owns states [32wv,32wv+32): A-frags preloaded (coalesced, 64 VGPR).
// x staged bf16 in swizzled LDS (one buffer per tile). All global loads for
// both tiles issue at kernel start; 3 raw barriers; red[] per tile.
__global__ __launch_bounds__(256, 3) void qnn_main(
    const float* __restrict__ x, const short* __restrict__ W,
    float* __restrict__ out, int niter, int stride) {
  const int tid = threadIdx.x;
  const int l   = tid & 63;
  const int wv  = tid >> 6;
  const int col = l & 31;
  const int h   = l >> 5;

  __shared__ short8 sB[2][1024];      // 2 x (64 rows x 16 chunks), 32 KiB
  __shared__ float  red[2][4][64][7]; // pad 7: conflict-free TAIL reads

  const int t0 = blockIdx.x;
  const int t1 = blockIdx.x + stride;

  // ---- issue ALL x loads first (HBM latency starts ticking now)
  float4 r0[8], r1[8];
  {
    const int pp = tid;                  // thread -> (row, chunk-pair)
    const int r = pp >> 2, q = pp & 3;   // 256 threads: 64 rows x 4 qpairs
    const float* gp0 = x + (size_t)(t0 * 64 + r) * 128 + q * 32;
    #pragma unroll
    for (int i = 0; i < 4; ++i)
      r0[i] = *reinterpret_cast<const float4*>(gp0 + i * 8);
    #pragma unroll
    for (int i = 0; i < 4; ++i)
      r0[4 + i] = *reinterpret_cast<const float4*>(gp0 + i * 8 + 4);
    if (t1 < niter) {
      const float* gp1 = x + (size_t)(t1 * 64 + r) * 128 + q * 32;
      #pragma unroll
      for (int i = 0; i < 4; ++i)
        r1[i] = *reinterpret_cast<const float4*>(gp1 + i * 8);
      #pragma unroll
      for (int i = 0; i < 4; ++i)
        r1[4 + i] = *reinterpret_cast<const float4*>(gp1 + i * 8 + 4);
    }
  }

  // ---- A-preload: coalesced fragment-order reads (L2-resident W)
  short8 A0[8], A1[8];
  #pragma unroll
  for (int j = 0; j < 8; ++j) {
    const int off = ((wv * 8 + j) * 64 + l) * 8;
    A0[j] = *reinterpret_cast<const short8*>(W + off);
    A1[j] = *reinterpret_cast<const short8*>(W + 16384 + off);
  }

  // thread covers rows r, chunks 4q.. (4 short8 chunks = 32 k-values x2)
  auto STAGE = [&](int buf, float4* rr) {
    const int r = tid >> 2, q4 = (tid & 3) * 4;
    #pragma unroll
    for (int i = 0; i < 4; ++i) {
      short8 c;
      c[0]=f2bf(rr[i].x);   c[1]=f2bf(rr[i].y);
      c[2]=f2bf(rr[i].z);   c[3]=f2bf(rr[i].w);
      c[4]=f2bf(rr[4+i].x); c[5]=f2bf(rr[4+i].y);
      c[6]=f2bf(rr[4+i].z); c[7]=f2bf(rr[4+i].w);
      const int q = q4 + i;
      sB[buf][r * 16 + (q ^ (r & 7))] = c;
    }
  };

  auto COMPUTE = [&](int rb) {
    const short8* xbuf = sB[rb];
    #pragma unroll
    for (int g = 0; g < 2; ++g) {
      f32x16 acc0 = {0.f,0.f,0.f,0.f,0.f,0.f,0.f,0.f,
                     0.f,0.f,0.f,0.f,0.f,0.f,0.f,0.f};
      f32x16 acc1 = {0.f,0.f,0.f,0.f,0.f,0.f,0.f,0.f,
                     0.f,0.f,0.f,0.f,0.f,0.f,0.f,0.f};
      const int r = g * 32 + col;
      #pragma unroll
      for (int j = 0; j < 8; ++j) {
        const int q = j * 2 + h;
        const short8 bfr = xbuf[r * 16 + (q ^ (r & 7))];
        acc0 = __builtin_amdgcn_mfma_f32_32x32x16_bf16(A0[j], bfr, acc0, 0, 0, 0);
        acc1 = __builtin_amdgcn_mfma_f32_32x32x16_bf16(A1[j], bfr, acc1, 0, 0, 0);
      }
      // Walsh tree over s-bits (verified rounds 0-3)
      float aS[8], aD[8];
      #pragma unroll
      for (int i = 0; i < 8; ++i) {
        const float pe = acc0[2*i]   * acc0[2*i]   + acc1[2*i]   * acc1[2*i];
        const float po = acc0[2*i+1] * acc0[2*i+1] + acc1[2*i+1] * acc1[2*i+1];
        aS[i] = pe + po;
        aD[i] = pe - po;
      }
      float bS[4], bD[4];
      #pragma unroll
      for (int i = 0; i < 4; ++i) {
        bS[i] = aS[2*i] + aS[2*i+1];
        bD[i] = aS[2*i] - aS[2*i+1];
      }
      float u0 = ((aD[0]+aD[1]) + (aD[2]+aD[3])) + ((aD[4]+aD[5]) + (aD[6]+aD[7]));
      float u1 = (bD[0] + bD[1]) + (bD[2] + bD[3]);
      const float cS0 = bS[0] + bS[1], cD0 = bS[0] - bS[1];
      const float cS1 = bS[2] + bS[3], cD1 = bS[2] - bS[3];
      float u3 = cD0 + cD1;
      float u4 = cS0 - cS1;
      float T  = cS0 + cS1;

      const float Tp = __shfl_xor(T, 32);
      const float u2 = h ? (Tp - T) : (T - Tp);
      T += Tp;
      u0 += __shfl_xor(u0, 32);
      u1 += __shfl_xor(u1, 32);
      u3 += __shfl_xor(u3, 32);
      u4 += __shfl_xor(u4, 32);

      if (h == 0) {
        red[rb][wv][r][0] = T;
        red[rb][wv][r][1] = u0;
        red[rb][wv][r][2] = u1;
        red[rb][wv][r][3] = u2;
        red[rb][wv][r][4] = u3;
        red[rb][wv][r][5] = u4;
      }
    }
  };

  auto TAIL = [&](int rb, int T) {
    if (tid < 64) {
      const int c = tid;
      const float T0 = red[rb][0][c][0], T1 = red[rb][1][c][0];
      const float T2 = red[rb][2][c][0], T3 = red[rb][3][c][0];
      const float sT  = (T0 + T1) + (T2 + T3);
      const float inv = 1.0f / sT;          // == 1/||x||^2 (unitarity)
      const float z0 = (T0 + T1) - (T2 + T3);
      const float z1 = (T0 - T1) + (T2 - T3);
      float zr[5];
      #pragma unroll
      for (int i = 0; i < 5; ++i)
        zr[i] = (red[rb][0][c][5-i] + red[rb][1][c][5-i]) +
                (red[rb][2][c][5-i] + red[rb][3][c][5-i]);
      float* o = out + (size_t)(T * 64 + c) * 7;
      o[0] = z0 * inv; o[1] = z1 * inv; o[2] = zr[0] * inv; o[3] = zr[1] * inv;
      o[4] = zr[2] * inv; o[5] = zr[3] * inv; o[6] = zr[4] * inv;
    }
  };

  STAGE(0, r0);
  asm volatile("s_waitcnt lgkmcnt(0)" ::: "memory");
  __builtin_amdgcn_s_barrier();
  asm volatile("" ::: "memory");

  COMPUTE(0);
  if (t1 < niter) STAGE(1, r1);
  asm volatile("s_waitcnt lgkmcnt(0)" ::: "memory");
  __builtin_amdgcn_s_barrier();
  asm volatile("" ::: "memory");

  if (t1 < niter) COMPUTE(1);
  TAIL(0, t0);
  asm volatile("s_waitcnt lgkmcnt(0)" ::: "memory");
  __builtin_amdgcn_s_barrier();
  asm volatile("" ::: "memory");

  if (t1 < niter) TAIL(1, t1);
}

// ------------------------------- launcher ----------------------------------
extern "C" void kernel_launch(void* const* d_in, const int* in_sizes, int n_in,
                              void* d_out, int out_size, void* d_ws, size_t ws_size,
                              hipStream_t stream) {
  const float* x   = (const float*)d_in[0];
  const float* wts = (const float*)d_in[1];
  float* out = (float*)d_out;
  short* W   = (short*)d_ws;               // 2 * 128*128 bf16 = 64 KiB

  const int B     = in_sizes[0] / 128;
  const int niter = B / 64;                // 64-row tiles
  const int grid  = (niter + 1) / 2;       // 2 tiles per block

  qnn_build_w<<<128, 64, 0, stream>>>(wts, W);
  qnn_main<<<grid, 256, 0, stream>>>(x, W, out, niter, grid);
}

// Round 5
// 24.204 us; speedup vs baseline: 1.3529x; 1.0761x over previous
//
#include <hip/hip_runtime.h>
#include <hip/hip_bf16.h>

// ---------------------------------------------------------------------------
// QuantumNeuralNetwork: out[b][q] = <psi_b| U^dag Z_q U |psi_b>.
// Kernel 1: build W = [Re(U); Im(U)] as 128x128 bf16 x2 in d_ws, stored in
//           MFMA-A-fragment order (coalesced per-wave preload).
// Kernel 2: ONE 64-row tile per block (grid = B/64 = 2048). Block does:
//           issue x loads -> A preload -> stage bf16 to swizzled LDS ->
//           barrier -> MFMA + Walsh epilogue -> barrier -> tail write.
//           Latency hiding comes from 4 blocks/CU TLP (16 waves/CU).
// ---------------------------------------------------------------------------

typedef __attribute__((ext_vector_type(8)))  short short8;   // 8 x bf16
typedef __attribute__((ext_vector_type(16))) float f32x16;   // 32x32 acc

static __device__ __forceinline__ short f2bf(float f) {
  __bf16 h = (__bf16)f;
  return __builtin_bit_cast(short, h);
}

// A-fragment layout: frag(P, wv=s>>5, j=k>>4); lane = (s&31) + 32*((k>>3)&1);
// elem = k&7.  Flat short index:
static __device__ __forceinline__ int widx(int P, int s, int k) {
  return ((((P << 2) + (s >> 5)) * 8 + (k >> 4)) * 64 +
          ((s & 31) + ((k >> 3) & 1) * 32)) * 8 + (k & 7);
}

// ------------------------------- kernel 1 ----------------------------------
// 128 blocks (one column k each) x 64 threads. Lane l holds states 2l, 2l+1.
__global__ void qnn_build_w(const float* __restrict__ wts,
                            short* __restrict__ W) {
  const int k = blockIdx.x;
  const int l = threadIdx.x;

  float c0r = (2 * l     == k) ? 1.f : 0.f, c0i = 0.f;
  float c1r = (2 * l + 1 == k) ? 1.f : 0.f, c1i = 0.f;

  for (int layer = 0; layer < 2; ++layer) {
    for (int q = 0; q < 7; ++q) {
      const float t0 = 0.5f * wts[(layer * 7 + q) * 3 + 0];
      const float t1 = 0.5f * wts[(layer * 7 + q) * 3 + 1];
      const float t2 = 0.5f * wts[(layer * 7 + q) * 3 + 2];
      const float cx = __cosf(t0), sx = __sinf(t0);
      const float cy = __cosf(t1), sy = __sinf(t1);
      const float cz = __cosf(t2), sz = __sinf(t2);
      const float m00r =  cy * cx, m00i =  sy * sx;
      const float m01r = -sy * cx, m01i = -cy * sx;
      const float m10r =  sy * cx, m10i = -cy * sx;
      const float m11r =  cy * cx, m11i = -sy * sx;
      const float g00r = m00r * cz + m00i * sz, g00i = m00i * cz - m00r * sz;
      const float g01r = m01r * cz + m01i * sz, g01i = m01i * cz - m01r * sz;
      const float g10r = m10r * cz - m10i * sz, g10i = m10i * cz + m10r * sz;
      const float g11r = m11r * cz - m11i * sz, g11i = m11i * cz + m11r * sz;

      const int b = 6 - q;
      if (b == 0) {
        const float n0r = g00r*c0r - g00i*c0i + g01r*c1r - g01i*c1i;
        const float n0i = g00r*c0i + g00i*c0r + g01r*c1i + g01i*c1r;
        const float n1r = g10r*c0r - g10i*c0i + g11r*c1r - g11i*c1i;
        const float n1i = g10r*c0i + g10i*c0r + g11r*c1i + g11i*c1r;
        c0r = n0r; c0i = n0i; c1r = n1r; c1i = n1i;
      } else {
        const int xm  = 1 << (b - 1);
        const int myb = (l >> (b - 1)) & 1;
        const float p0r = __shfl_xor(c0r, xm), p0i = __shfl_xor(c0i, xm);
        const float p1r = __shfl_xor(c1r, xm), p1i = __shfl_xor(c1i, xm);
        const float gar = myb ? g11r : g00r, gai = myb ? g11i : g00i;
        const float gbr = myb ? g10r : g01r, gbi = myb ? g10i : g01i;
        const float n0r = gar*c0r - gai*c0i + gbr*p0r - gbi*p0i;
        const float n0i = gar*c0i + gai*c0r + gbr*p0i + gbi*p0r;
        const float n1r = gar*c1r - gai*c1i + gbr*p1r - gbi*p1i;
        const float n1i = gar*c1i + gai*c1r + gbr*p1i + gbi*p1r;
        c0r = n0r; c0i = n0i; c1r = n1r; c1i = n1i;
      }
    }
    #pragma unroll
    for (int q = 0; q < 7; ++q) {
      const int bc = 6 - q;
      const int bt = 6 - ((q + 1) % 7);
      if (bt == 0) {
        if (l & 1) { float tr=c0r, ti=c0i; c0r=c1r; c0i=c1i; c1r=tr; c1i=ti; }
      } else if (bc == 0) {
        c1r = __shfl_xor(c1r, 32);
        c1i = __shfl_xor(c1i, 32);
      } else {
        const int xm = 1 << (bt - 1);
        const float p0r = __shfl_xor(c0r, xm), p0i = __shfl_xor(c0i, xm);
        const float p1r = __shfl_xor(c1r, xm), p1i = __shfl_xor(c1i, xm);
        if ((l >> (bc - 1)) & 1) { c0r=p0r; c0i=p0i; c1r=p1r; c1i=p1i; }
      }
    }
  }

  W[widx(0, 2 * l,     k)] = f2bf(c0r);
  W[widx(0, 2 * l + 1, k)] = f2bf(c1r);
  W[widx(1, 2 * l,     k)] = f2bf(c0i);
  W[widx(1, 2 * l + 1, k)] = f2bf(c1i);
}

// ------------------------------- kernel 2 ----------------------------------
// 256 threads (4 waves), ONE 64-row tile per block. Wave wv owns states
// [32wv,32wv+32) (A-frags, 64 VGPRs, coalesced fragment-order load).
// x loads: p = i*256+tid, row = p>>4, chunk = p&15 -> each wave instruction
// reads a contiguous aligned 1 KiB (best coalescing, verified round 1/2).
__global__ __launch_bounds__(256, 4) void qnn_main(
    const float* __restrict__ x, const short* __restrict__ W,
    float* __restrict__ out) {
  const int tid = threadIdx.x;
  const int l   = tid & 63;
  const int wv  = tid >> 6;
  const int col = l & 31;
  const int h   = l >> 5;

  __shared__ short8 xb[1024];         // 64 rows x 16 chunks (swizzled), 16 KiB
  __shared__ float  red[4][64][7];    // pad 7: conflict-free TAIL reads, 7 KiB

  const int t0 = blockIdx.x;

  // ---- issue x loads first (HBM latency starts now); contiguous mapping
  float4 fa[4], fb[4];
  #pragma unroll
  for (int i = 0; i < 4; ++i) {
    const int p = i * 256 + tid;
    const int r = p >> 4, q = p & 15;
    const float* gp = x + (size_t)(t0 * 64 + r) * 128 + q * 8;
    fa[i] = *reinterpret_cast<const float4*>(gp);
    fb[i] = *reinterpret_cast<const float4*>(gp + 4);
  }

  // ---- A-preload: coalesced fragment-order reads (W is L2-resident)
  short8 A0[8], A1[8];
  #pragma unroll
  for (int j = 0; j < 8; ++j) {
    const int off = ((wv * 8 + j) * 64 + l) * 8;
    A0[j] = *reinterpret_cast<const short8*>(W + off);
    A1[j] = *reinterpret_cast<const short8*>(W + 16384 + off);
  }

  // ---- stage: fp32 regs -> bf16 swizzled LDS
  #pragma unroll
  for (int i = 0; i < 4; ++i) {
    const int p = i * 256 + tid;
    const int r = p >> 4, q = p & 15;
    short8 c;
    c[0]=f2bf(fa[i].x); c[1]=f2bf(fa[i].y); c[2]=f2bf(fa[i].z); c[3]=f2bf(fa[i].w);
    c[4]=f2bf(fb[i].x); c[5]=f2bf(fb[i].y); c[6]=f2bf(fb[i].z); c[7]=f2bf(fb[i].w);
    xb[r * 16 + (q ^ (r & 7))] = c;
  }
  asm volatile("s_waitcnt lgkmcnt(0)" ::: "memory");
  __builtin_amdgcn_s_barrier();
  asm volatile("" ::: "memory");

  // ---- compute: per g-group 16 MFMA + Walsh-tree epilogue
  #pragma unroll
  for (int g = 0; g < 2; ++g) {
    f32x16 acc0 = {0.f,0.f,0.f,0.f,0.f,0.f,0.f,0.f,
                   0.f,0.f,0.f,0.f,0.f,0.f,0.f,0.f};
    f32x16 acc1 = {0.f,0.f,0.f,0.f,0.f,0.f,0.f,0.f,
                   0.f,0.f,0.f,0.f,0.f,0.f,0.f,0.f};
    const int r = g * 32 + col;
    #pragma unroll
    for (int j = 0; j < 8; ++j) {
      const int q = j * 2 + h;
      const short8 bfr = xb[r * 16 + (q ^ (r & 7))];
      acc0 = __builtin_amdgcn_mfma_f32_32x32x16_bf16(A0[j], bfr, acc0, 0, 0, 0);
      acc1 = __builtin_amdgcn_mfma_f32_32x32x16_bf16(A1[j], bfr, acc1, 0, 0, 0);
    }
    // Walsh tree over s-bits (verified rounds 0-4)
    float aS[8], aD[8];
    #pragma unroll
    for (int i = 0; i < 8; ++i) {
      const float pe = acc0[2*i]   * acc0[2*i]   + acc1[2*i]   * acc1[2*i];
      const float po = acc0[2*i+1] * acc0[2*i+1] + acc1[2*i+1] * acc1[2*i+1];
      aS[i] = pe + po;
      aD[i] = pe - po;
    }
    float bS[4], bD[4];
    #pragma unroll
    for (int i = 0; i < 4; ++i) {
      bS[i] = aS[2*i] + aS[2*i+1];
      bD[i] = aS[2*i] - aS[2*i+1];
    }
    float u0 = ((aD[0]+aD[1]) + (aD[2]+aD[3])) + ((aD[4]+aD[5]) + (aD[6]+aD[7]));
    float u1 = (bD[0] + bD[1]) + (bD[2] + bD[3]);
    const float cS0 = bS[0] + bS[1], cD0 = bS[0] - bS[1];
    const float cS1 = bS[2] + bS[3], cD1 = bS[2] - bS[3];
    float u3 = cD0 + cD1;
    float u4 = cS0 - cS1;
    float T  = cS0 + cS1;

    const float Tp = __shfl_xor(T, 32);
    const float u2 = h ? (Tp - T) : (T - Tp);
    T += Tp;
    u0 += __shfl_xor(u0, 32);
    u1 += __shfl_xor(u1, 32);
    u3 += __shfl_xor(u3, 32);
    u4 += __shfl_xor(u4, 32);

    if (h == 0) {
      red[wv][r][0] = T;
      red[wv][r][1] = u0;
      red[wv][r][2] = u1;
      red[wv][r][3] = u2;
      red[wv][r][4] = u3;
      red[wv][r][5] = u4;
    }
  }

  asm volatile("s_waitcnt lgkmcnt(0)" ::: "memory");
  __builtin_amdgcn_s_barrier();
  asm volatile("" ::: "memory");

  // ---- tail: combine across waves (s-bits b5,b6), write 7 outs x 64 rows
  if (tid < 64) {
    const int c = tid;
    const float T0 = red[0][c][0], T1 = red[1][c][0];
    const float T2 = red[2][c][0], T3 = red[3][c][0];
    const float sT  = (T0 + T1) + (T2 + T3);
    const float inv = 1.0f / sT;            // == 1/||x||^2 (unitarity)
    const float z0 = (T0 + T1) - (T2 + T3);
    const float z1 = (T0 - T1) + (T2 - T3);
    float zr[5];
    #pragma unroll
    for (int i = 0; i < 5; ++i)
      zr[i] = (red[0][c][5-i] + red[1][c][5-i]) +
              (red[2][c][5-i] + red[3][c][5-i]);
    float* o = out + (size_t)(t0 * 64 + c) * 7;
    o[0] = z0 * inv; o[1] = z1 * inv; o[2] = zr[0] * inv; o[3] = zr[1] * inv;
    o[4] = zr[2] * inv; o[5] = zr[3] * inv; o[6] = zr[4] * inv;
  }
}

// ------------------------------- launcher ----------------------------------
extern "C" void kernel_launch(void* const* d_in, const int* in_sizes, int n_in,
                              void* d_out, int out_size, void* d_ws, size_t ws_size,
                              hipStream_t stream) {
  const float* x   = (const float*)d_in[0];
  const float* wts = (const float*)d_in[1];
  float* out = (float*)d_out;
  short* W   = (short*)d_ws;               // 2 * 128*128 bf16 = 64 KiB

  const int B     = in_sizes[0] / 128;
  const int grid  = B / 64;                // one 64-row tile per block

  qnn_build_w<<<128, 64, 0, stream>>>(wts, W);
  qnn_main<<<grid, 256, 0, stream>>>(x, W, out);
}